// Round 5
// baseline (198.965 us; speedup 1.0000x reference)
//
#include <hip/hip_runtime.h>

#define NNODES 10000
#define NHEADS 8
#define DHEAD 64
#define FEAT 512
#define NNETS 3
#define EDGES 160000
#define ETOT (NNETS * EDGES)
#define NPASS 4
#define NBLK ((NNODES + 3) / 4)   // node-blocks per pass (4 nodes/block)

typedef unsigned short ushort_t;
typedef __bf16 bf16x8 __attribute__((ext_vector_type(8)));
typedef float f32x4 __attribute__((ext_vector_type(4)));

static __device__ __forceinline__ float b2f(ushort_t u) {
    return __uint_as_float(((unsigned)u) << 16);
}
static __device__ __forceinline__ ushort_t f2b(float f) {
    unsigned u = __float_as_uint(f);
    unsigned r = u + 0x7FFF + ((u >> 16) & 1);   // RNE
    return (ushort_t)(r >> 16);
}

static __device__ __forceinline__ void mfma16(f32x4& d, bf16x8 a, bf16x8 b) {
    asm volatile("v_mfma_f32_16x16x32_bf16 %0, %1, %2, %0" : "+v"(d) : "v"(a), "v"(b));
}

#define GLDS(gp, lp)                                                                     \
    __builtin_amdgcn_global_load_lds((const __attribute__((address_space(1))) void*)(gp), \
                                     (__attribute__((address_space(3))) void*)(lp), 16, 0, 0)

// ---------------- inv[n_id[i]] = i ----------------
__global__ __launch_bounds__(256) void build_inv_kernel(const int* __restrict__ n_id,
                                                        int* __restrict__ inv) {
    int i = blockIdx.x * 256 + threadIdx.x;
    if (i < NNODES) inv[n_id[i]] = i;
}

// ---------------- histogram of dst ----------------
__global__ __launch_bounds__(256) void hist_kernel(const int* __restrict__ edges,
                                                   const int* __restrict__ inv,
                                                   int* __restrict__ counts) {
    int eid = blockIdx.x * 256 + threadIdx.x;
    if (eid >= ETOT) return;
    int net = eid / EDGES;
    int e = eid - net * EDGES;
    int dstg = edges[net * (2 * EDGES) + EDGES + e];
    int dst = inv[dstg];
    atomicAdd(&counts[dst], 1);
}

// ---------------- exclusive scan of counts -> offsets[NNODES+1] ----------------
__global__ __launch_bounds__(1024) void scan_kernel(const int* __restrict__ counts,
                                                    int* __restrict__ offsets) {
    __shared__ int partial[1024];
    int t = threadIdx.x;
    const int PER = (NNODES + 1023) / 1024;  // 10
    int base = t * PER;
    int s = 0;
    for (int i = 0; i < PER; ++i) {
        int idx = base + i;
        if (idx < NNODES) s += counts[idx];
    }
    partial[t] = s;
    __syncthreads();
    for (int off = 1; off < 1024; off <<= 1) {
        int v = (t >= off) ? partial[t - off] : 0;
        __syncthreads();
        partial[t] += v;
        __syncthreads();
    }
    int running = (t == 0) ? 0 : partial[t - 1];
    for (int i = 0; i < PER; ++i) {
        int idx = base + i;
        if (idx < NNODES) {
            offsets[idx] = running;
            running += counts[idx];
        }
    }
    if (NNODES >= base && NNODES < base + PER) offsets[NNODES] = running;
}

// ---- scatter + alpha-prep fused: dst-sorted src + per-pass packed head-pair alpha ----
__global__ __launch_bounds__(256) void scatter_kernel(const int* __restrict__ edges,
                                                      const int* __restrict__ inv,
                                                      const int* __restrict__ offsets,
                                                      int* __restrict__ cursor,
                                                      const float* __restrict__ attns,
                                                      const float* __restrict__ nw,
                                                      int* __restrict__ src_sorted,
                                                      unsigned* __restrict__ alphau) {
    int eid = blockIdx.x * 256 + threadIdx.x;
    if (eid >= ETOT) return;
    int net = eid / EDGES;
    int e = eid - net * EDGES;
    int srcg = edges[net * (2 * EDGES) + e];
    int dstg = edges[net * (2 * EDGES) + EDGES + e];
    int dst = inv[dstg];
    int pos = offsets[dst] + atomicAdd(&cursor[dst], 1);
    src_sorted[pos] = inv[srcg];
    float4 A0 = *(const float4*)(&attns[(size_t)eid * NHEADS]);
    float4 A1 = *(const float4*)(&attns[(size_t)eid * NHEADS + 4]);
    unsigned w0 = (unsigned)f2b(A0.x * nw[0 * NNETS + net]) |
                  ((unsigned)f2b(A0.y * nw[1 * NNETS + net]) << 16);
    unsigned w1 = (unsigned)f2b(A0.z * nw[2 * NNETS + net]) |
                  ((unsigned)f2b(A0.w * nw[3 * NNETS + net]) << 16);
    unsigned w2 = (unsigned)f2b(A1.x * nw[4 * NNETS + net]) |
                  ((unsigned)f2b(A1.y * nw[5 * NNETS + net]) << 16);
    unsigned w3 = (unsigned)f2b(A1.z * nw[6 * NNETS + net]) |
                  ((unsigned)f2b(A1.w * nw[7 * NNETS + net]) << 16);
    alphau[(size_t)0 * ETOT + pos] = w0;
    alphau[(size_t)1 * ETOT + pos] = w1;
    alphau[(size_t)2 * ETOT + pos] = w2;
    alphau[(size_t)3 * ETOT + pos] = w3;
}

// ---------------- x (f32) -> xb (bf16) ----------------
__global__ __launch_bounds__(256) void cvt_x_kernel(const float* __restrict__ x,
                                                    ushort_t* __restrict__ xb) {
    int i = (blockIdx.x * 256 + threadIdx.x) * 4;
    if (i < NNODES * FEAT) {
        float4 v = *(const float4*)(x + i);
        ushort4 o;
        o.x = f2b(v.x);
        o.y = f2b(v.y);
        o.z = f2b(v.z);
        o.w = f2b(v.w);
        *(ushort4*)(xb + i) = o;
    }
}

// ---------------- W (f32, KxN) -> wbt (bf16, NxK transposed) ----------------
__global__ __launch_bounds__(256) void cvt_wt_kernel(const float* __restrict__ W,
                                                     ushort_t* __restrict__ wbt) {
    __shared__ float tile[32][33];
    int k0 = blockIdx.y * 32, n0 = blockIdx.x * 32;
    int t = threadIdx.x;
    int r = t >> 3, c4 = (t & 7) * 4;
    float4 v = *(const float4*)(&W[(size_t)(k0 + r) * FEAT + n0 + c4]);
    tile[r][c4 + 0] = v.x;
    tile[r][c4 + 1] = v.y;
    tile[r][c4 + 2] = v.z;
    tile[r][c4 + 3] = v.w;
    __syncthreads();
    ushort4 o;
    o.x = f2b(tile[c4 + 0][r]);
    o.y = f2b(tile[c4 + 1][r]);
    o.z = f2b(tile[c4 + 2][r]);
    o.w = f2b(tile[c4 + 3][r]);
    *(ushort4*)(&wbt[(size_t)(n0 + r) * FEAT + k0 + c4]) = o;
}

// ---- hfeat = xb @ wbt^T (bf16 MFMA); epilogue writes 4 regions [N][D][2heads] ----
__global__ __launch_bounds__(256) void gemm_mfma_kernel(const ushort_t* __restrict__ xb,
                                                        const ushort_t* __restrict__ wbt,
                                                        ushort_t* __restrict__ Cq) {
    __shared__ ushort_t Alds[128 * 32];
    __shared__ ushort_t Blds[128 * 32];
    const int t = threadIdx.x;
    const int wv = t >> 6;
    const int l = t & 63;
    const int lane15 = l & 15;
    const int hi = l >> 4;
    const int r0 = blockIdx.y * 128;
    const int c0 = blockIdx.x * 128;
    const int WR = (wv >> 1) * 64;
    const int WC = (wv & 1) * 64;

    const int srow = (wv << 4) + (l >> 2);
    const int scol = (l & 3) << 3;
    const ushort_t* Ab0 = xb + (size_t)min(r0 + srow, NNODES - 1) * FEAT + scol;
    const ushort_t* Ab1 = xb + (size_t)min(r0 + 64 + srow, NNODES - 1) * FEAT + scol;
    const ushort_t* Bb0 = wbt + (size_t)(c0 + srow) * FEAT + scol;
    const ushort_t* Bb1 = wbt + (size_t)(c0 + 64 + srow) * FEAT + scol;
    ushort_t* Al0 = &Alds[wv * 512];
    ushort_t* Al1 = &Alds[2048 + wv * 512];
    ushort_t* Bl0 = &Blds[wv * 512];
    ushort_t* Bl1 = &Blds[2048 + wv * 512];

    f32x4 acc[4][4] = {};

    for (int k0 = 0; k0 < FEAT; k0 += 32) {
        GLDS(Ab0 + k0, Al0);
        GLDS(Ab1 + k0, Al1);
        GLDS(Bb0 + k0, Bl0);
        GLDS(Bb1 + k0, Bl1);
        __syncthreads();
        bf16x8 a[4], b[4];
        const ushort_t* Ap = &Alds[(WR + lane15) * 32 + hi * 8];
        const ushort_t* Bp = &Blds[(WC + lane15) * 32 + hi * 8];
#pragma unroll
        for (int m = 0; m < 4; ++m) a[m] = *(const bf16x8*)(Ap + m * 512);
#pragma unroll
        for (int n = 0; n < 4; ++n) b[n] = *(const bf16x8*)(Bp + n * 512);
#pragma unroll
        for (int m = 0; m < 4; ++m)
#pragma unroll
            for (int n = 0; n < 4; ++n) mfma16(acc[m][n], a[m], b[n]);
        __syncthreads();
    }
    asm volatile("s_nop 7\n\ts_nop 7\n\ts_nop 7" ::);  // MFMA->VALU hazard guard
    // col -> head h = col>>6, d = col&63; region p = h>>1, slot = h&1
    const int h = (c0 + WC) >> 6;  // head fixed per wave (64-col span)
    const int p = h >> 1;
    const int slot = h & 1;
    ushort_t* base = Cq + (size_t)p * NNODES * 128 + slot;
#pragma unroll
    for (int m = 0; m < 4; ++m) {
#pragma unroll
        for (int rr = 0; rr < 4; ++rr) {
            int row = r0 + WR + m * 16 + hi * 4 + rr;
            if (row < NNODES) {
#pragma unroll
                for (int n = 0; n < 4; ++n) {
                    int d = n * 16 + lane15;  // 0..63 within head
                    base[(size_t)row * 128 + d * 2] = f2b(acc[m][n][rr]);
                }
            }
        }
    }
}

// ---- aggregation: 1-D grid, pass p = blockIdx.x / NBLK (phase-separated dispatch), ----
// ---- 4 waves/block, 1 node/wave, lane = column d, head-pair (2p, 2p+1) per pass ----
static __device__ __forceinline__ void fma_pair(unsigned a, unsigned h, float& lo,
                                                float& hi) {
    float alo = __uint_as_float(a << 16);
    float ahi = __uint_as_float(a & 0xFFFF0000u);
    float hlo = __uint_as_float(h << 16);
    float hhi = __uint_as_float(h & 0xFFFF0000u);
    lo = fmaf(alo, hlo, lo);
    hi = fmaf(ahi, hhi, hi);
}

__global__ __launch_bounds__(256) void aggregate_kernel(
    const int* __restrict__ src_sorted, const int* __restrict__ offsets,
    const unsigned* __restrict__ alphau, const ushort_t* __restrict__ hfeatq,
    const float* __restrict__ bias, float* __restrict__ out) {
    int wv = threadIdx.x >> 6;
    int d = threadIdx.x & 63;
    int p = blockIdx.x / NBLK;                 // pass (phase-separated by dispatch order)
    int n = (blockIdx.x - p * NBLK) * 4 + wv;  // node
    if (n >= NNODES) return;
    int beg = offsets[n], end = offsets[n + 1];
    const unsigned* ap = alphau + (size_t)p * ETOT;
    const ushort_t* hp = hfeatq + (size_t)p * NNODES * 128 + d * 2;
    float accLo = 0.f, accHi = 0.f;
    int k = beg;
    for (; k + 3 < end; k += 4) {
        int s0 = __builtin_nontemporal_load(&src_sorted[k + 0]);
        int s1 = __builtin_nontemporal_load(&src_sorted[k + 1]);
        int s2 = __builtin_nontemporal_load(&src_sorted[k + 2]);
        int s3 = __builtin_nontemporal_load(&src_sorted[k + 3]);
        unsigned a0 = __builtin_nontemporal_load(&ap[k + 0]);
        unsigned a1 = __builtin_nontemporal_load(&ap[k + 1]);
        unsigned a2 = __builtin_nontemporal_load(&ap[k + 2]);
        unsigned a3 = __builtin_nontemporal_load(&ap[k + 3]);
        unsigned h0 = *(const unsigned*)(hp + (size_t)s0 * 128);
        unsigned h1 = *(const unsigned*)(hp + (size_t)s1 * 128);
        unsigned h2 = *(const unsigned*)(hp + (size_t)s2 * 128);
        unsigned h3 = *(const unsigned*)(hp + (size_t)s3 * 128);
        fma_pair(a0, h0, accLo, accHi);
        fma_pair(a1, h1, accLo, accHi);
        fma_pair(a2, h2, accLo, accHi);
        fma_pair(a3, h3, accLo, accHi);
    }
    for (; k < end; ++k) {
        int s0 = __builtin_nontemporal_load(&src_sorted[k]);
        unsigned a0 = __builtin_nontemporal_load(&ap[k]);
        unsigned h0 = *(const unsigned*)(hp + (size_t)s0 * 128);
        fma_pair(a0, h0, accLo, accHi);
    }
    int c0 = (2 * p) * DHEAD + d;
    int c1 = (2 * p + 1) * DHEAD + d;
    __builtin_nontemporal_store(accLo + bias[c0], &out[(size_t)n * FEAT + c0]);
    __builtin_nontemporal_store(accHi + bias[c1], &out[(size_t)n * FEAT + c1]);
}

extern "C" void kernel_launch(void* const* d_in, const int* in_sizes, int n_in,
                              void* d_out, int out_size, void* d_ws, size_t ws_size,
                              hipStream_t stream) {
    const float* x = (const float*)d_in[0];
    const int* n_id = (const int*)d_in[1];
    const float* attns = (const float*)d_in[2];
    const int* edges = (const int*)d_in[3];
    const float* nw = (const float*)d_in[4];
    const float* W = (const float*)d_in[5];
    const float* bias = (const float*)d_in[6];
    float* out = (float*)d_out;

    char* ws = (char*)d_ws;
    size_t o = 0;
    ushort_t* hfeatq = (ushort_t*)(ws + o); o += 10240000;   // 4x [N][64][2] bf16
    unsigned* alphau = (unsigned*)(ws + o); o += 7680000;    // 4x [Etot] packed bf16x2
    ushort_t* xb     = (ushort_t*)(ws + o); o += 10240000;
    ushort_t* wbt    = (ushort_t*)(ws + o); o += 524288;
    int* src_sorted  = (int*)(ws + o);      o += 1920000;
    int* counts      = (int*)(ws + o);      o += 40000;
    int* cursor      = (int*)(ws + o);      o += 40000;
    int* offsets     = (int*)(ws + o);      o += 40016;
    int* inv         = (int*)(ws + o);      o += 40000;
    // total ~30.8 MB

    hipMemsetAsync(counts, 0, 80000, stream);  // counts + cursor (adjacent)
    build_inv_kernel<<<(NNODES + 255) / 256, 256, 0, stream>>>(n_id, inv);
    hist_kernel<<<(ETOT + 255) / 256, 256, 0, stream>>>(edges, inv, counts);
    scan_kernel<<<1, 1024, 0, stream>>>(counts, offsets);
    scatter_kernel<<<(ETOT + 255) / 256, 256, 0, stream>>>(edges, inv, offsets, cursor,
                                                           attns, nw, src_sorted, alphau);
    cvt_x_kernel<<<(NNODES * FEAT / 4 + 255) / 256, 256, 0, stream>>>(x, xb);
    dim3 wgrid(FEAT / 32, FEAT / 32);
    cvt_wt_kernel<<<wgrid, 256, 0, stream>>>(W, wbt);
    dim3 ggrid(FEAT / 128, (NNODES + 127) / 128);
    gemm_mfma_kernel<<<ggrid, 256, 0, stream>>>(xb, wbt, hfeatq);
    aggregate_kernel<<<NPASS * NBLK, 256, 0, stream>>>(src_sorted, offsets, alphau,
                                                       hfeatq, bias, out);
}

// Round 6
// 193.591 us; speedup vs baseline: 1.0278x; 1.0278x over previous
//
#include <hip/hip_runtime.h>

#define NNODES 10000
#define NHEADS 8
#define DHEAD 64
#define FEAT 512
#define NNETS 3
#define EDGES 160000
#define ETOT (NNETS * EDGES)

#define CVTX_BLKS 5000          // NNODES*FEAT/4/256
#define CVTW_BLKS 256           // (FEAT/32)^2
#define HIST_BLKS 1875          // ETOT/256
#define INV_BLKS 40             // ceil(NNODES/256)

typedef unsigned short ushort_t;
typedef __bf16 bf16x8 __attribute__((ext_vector_type(8)));
typedef float f32x4 __attribute__((ext_vector_type(4)));
typedef unsigned u32x4 __attribute__((ext_vector_type(4)));

static __device__ __forceinline__ ushort_t f2b(float f) {
    unsigned u = __float_as_uint(f);
    unsigned r = u + 0x7FFF + ((u >> 16) & 1);   // RNE
    return (ushort_t)(r >> 16);
}
static __device__ __forceinline__ float b2f(ushort_t u) {
    return __uint_as_float(((unsigned)u) << 16);
}

static __device__ __forceinline__ void mfma16(f32x4& d, bf16x8 a, bf16x8 b) {
    asm volatile("v_mfma_f32_16x16x32_bf16 %0, %1, %2, %0" : "+v"(d) : "v"(a), "v"(b));
}

#define GLDS(gp, lp)                                                                     \
    __builtin_amdgcn_global_load_lds((const __attribute__((address_space(1))) void*)(gp), \
                                     (__attribute__((address_space(3))) void*)(lp), 16, 0, 0)

// ---- fused prep: cvt_x | cvt_wt | hist(global dst) | build_inv ----
__global__ __launch_bounds__(256) void prep_fused_kernel(
    const float* __restrict__ x, ushort_t* __restrict__ xb, const float* __restrict__ W,
    ushort_t* __restrict__ wbt, const int* __restrict__ edges, int* __restrict__ counts,
    const int* __restrict__ n_id, int* __restrict__ inv) {
    __shared__ float tile[32][33];
    int b = blockIdx.x;
    int t = threadIdx.x;
    if (b < CVTX_BLKS) {
        int i = (b * 256 + t) * 4;
        float4 v = *(const float4*)(x + i);
        ushort4 o;
        o.x = f2b(v.x);
        o.y = f2b(v.y);
        o.z = f2b(v.z);
        o.w = f2b(v.w);
        *(ushort4*)(xb + i) = o;
    } else if (b < CVTX_BLKS + CVTW_BLKS) {
        int bb = b - CVTX_BLKS;
        int n0 = (bb & 15) * 32, k0 = (bb >> 4) * 32;
        int r = t >> 3, c4 = (t & 7) * 4;
        float4 v = *(const float4*)(&W[(size_t)(k0 + r) * FEAT + n0 + c4]);
        tile[r][c4 + 0] = v.x;
        tile[r][c4 + 1] = v.y;
        tile[r][c4 + 2] = v.z;
        tile[r][c4 + 3] = v.w;
        __syncthreads();
        ushort4 o;
        o.x = f2b(tile[c4 + 0][r]);
        o.y = f2b(tile[c4 + 1][r]);
        o.z = f2b(tile[c4 + 2][r]);
        o.w = f2b(tile[c4 + 3][r]);
        *(ushort4*)(&wbt[(size_t)(n0 + r) * FEAT + k0 + c4]) = o;
    } else if (b < CVTX_BLKS + CVTW_BLKS + HIST_BLKS) {
        int eid = (b - CVTX_BLKS - CVTW_BLKS) * 256 + t;
        int net = eid / EDGES;
        int e = eid - net * EDGES;
        int dstg = edges[net * (2 * EDGES) + EDGES + e];
        atomicAdd(&counts[dstg], 1);
    } else {
        int i = (b - CVTX_BLKS - CVTW_BLKS - HIST_BLKS) * 256 + t;
        if (i < NNODES) inv[n_id[i]] = i;
    }
}

// ---------------- exclusive scan of counts -> offsets[NNODES+1] ----------------
__global__ __launch_bounds__(1024) void scan_kernel(const int* __restrict__ counts,
                                                    int* __restrict__ offsets) {
    __shared__ int partial[1024];
    int t = threadIdx.x;
    const int PER = (NNODES + 1023) / 1024;  // 10
    int base = t * PER;
    int s = 0;
    for (int i = 0; i < PER; ++i) {
        int idx = base + i;
        if (idx < NNODES) s += counts[idx];
    }
    partial[t] = s;
    __syncthreads();
    for (int off = 1; off < 1024; off <<= 1) {
        int v = (t >= off) ? partial[t - off] : 0;
        __syncthreads();
        partial[t] += v;
        __syncthreads();
    }
    int running = (t == 0) ? 0 : partial[t - 1];
    for (int i = 0; i < PER; ++i) {
        int idx = base + i;
        if (idx < NNODES) {
            offsets[idx] = running;
            running += counts[idx];
        }
    }
    if (NNODES >= base && NNODES < base + PER) offsets[NNODES] = running;
}

// ---- scatter by global dst: byte-offset src + [Etot][8] bf16 alpha ----
__global__ __launch_bounds__(256) void scatter_kernel(const int* __restrict__ edges,
                                                      const int* __restrict__ inv,
                                                      const int* __restrict__ offsets,
                                                      int* __restrict__ cursor,
                                                      const float* __restrict__ attns,
                                                      const float* __restrict__ nw,
                                                      int* __restrict__ srcoff,
                                                      ushort_t* __restrict__ alphab) {
    int eid = blockIdx.x * 256 + threadIdx.x;
    int net = eid / EDGES;
    int e = eid - net * EDGES;
    int srcg = edges[net * (2 * EDGES) + e];
    int dstg = edges[net * (2 * EDGES) + EDGES + e];
    int pos = offsets[dstg] + atomicAdd(&cursor[dstg], 1);
    srcoff[pos] = inv[srcg] << 10;  // byte offset of hfeat row (1024 B/row)
    float4 A0 = *(const float4*)(&attns[(size_t)eid * NHEADS]);
    float4 A1 = *(const float4*)(&attns[(size_t)eid * NHEADS + 4]);
    ushort4 o0, o1;
    o0.x = f2b(A0.x * nw[0 * NNETS + net]);
    o0.y = f2b(A0.y * nw[1 * NNETS + net]);
    o0.z = f2b(A0.z * nw[2 * NNETS + net]);
    o0.w = f2b(A0.w * nw[3 * NNETS + net]);
    o1.x = f2b(A1.x * nw[4 * NNETS + net]);
    o1.y = f2b(A1.y * nw[5 * NNETS + net]);
    o1.z = f2b(A1.z * nw[6 * NNETS + net]);
    o1.w = f2b(A1.w * nw[7 * NNETS + net]);
    *(ushort4*)(&alphab[(size_t)pos * NHEADS]) = o0;
    *(ushort4*)(&alphab[(size_t)pos * NHEADS + 4]) = o1;
}

// ---- hfeat = xb @ wbt^T (bf16 MFMA, 128x128 tile), epilogue writes [N][D][H] ----
__global__ __launch_bounds__(256) void gemm_mfma_kernel(const ushort_t* __restrict__ xb,
                                                        const ushort_t* __restrict__ wbt,
                                                        ushort_t* __restrict__ Cq) {
    __shared__ ushort_t Alds[128 * 32];
    __shared__ ushort_t Blds[128 * 32];
    const int t = threadIdx.x;
    const int wv = t >> 6;
    const int l = t & 63;
    const int lane15 = l & 15;
    const int hi = l >> 4;
    const int r0 = blockIdx.y * 128;
    const int c0 = blockIdx.x * 128;
    const int WR = (wv >> 1) * 64;
    const int WC = (wv & 1) * 64;

    const int srow = (wv << 4) + (l >> 2);
    const int scol = (l & 3) << 3;
    const ushort_t* Ab0 = xb + (size_t)min(r0 + srow, NNODES - 1) * FEAT + scol;
    const ushort_t* Ab1 = xb + (size_t)min(r0 + 64 + srow, NNODES - 1) * FEAT + scol;
    const ushort_t* Bb0 = wbt + (size_t)(c0 + srow) * FEAT + scol;
    const ushort_t* Bb1 = wbt + (size_t)(c0 + 64 + srow) * FEAT + scol;
    ushort_t* Al0 = &Alds[wv * 512];
    ushort_t* Al1 = &Alds[2048 + wv * 512];
    ushort_t* Bl0 = &Blds[wv * 512];
    ushort_t* Bl1 = &Blds[2048 + wv * 512];

    f32x4 acc[4][4] = {};

    for (int k0 = 0; k0 < FEAT; k0 += 32) {
        GLDS(Ab0 + k0, Al0);
        GLDS(Ab1 + k0, Al1);
        GLDS(Bb0 + k0, Bl0);
        GLDS(Bb1 + k0, Bl1);
        __syncthreads();
        bf16x8 a[4], b[4];
        const ushort_t* Ap = &Alds[(WR + lane15) * 32 + hi * 8];
        const ushort_t* Bp = &Blds[(WC + lane15) * 32 + hi * 8];
#pragma unroll
        for (int m = 0; m < 4; ++m) a[m] = *(const bf16x8*)(Ap + m * 512);
#pragma unroll
        for (int n = 0; n < 4; ++n) b[n] = *(const bf16x8*)(Bp + n * 512);
#pragma unroll
        for (int m = 0; m < 4; ++m)
#pragma unroll
            for (int n = 0; n < 4; ++n) mfma16(acc[m][n], a[m], b[n]);
        __syncthreads();
    }
    asm volatile("s_nop 7\n\ts_nop 7\n\ts_nop 7" ::);  // MFMA->VALU hazard guard
    const int h = (c0 + WC) >> 6;  // head fixed per wave (64-col span)
#pragma unroll
    for (int m = 0; m < 4; ++m) {
#pragma unroll
        for (int rr = 0; rr < 4; ++rr) {
            int row = r0 + WR + m * 16 + hi * 4 + rr;
            if (row < NNODES) {
#pragma unroll
                for (int n = 0; n < 4; ++n) {
                    int d = n * 16 + lane15;  // 0..63 within head
                    Cq[(size_t)row * FEAT + d * NHEADS + h] = f2b(acc[m][n][rr]);
                }
            }
        }
    }
}

// ---- aggregation: 1 node-pair per wave, lane = column d, unroll 8 edges ----
static __device__ __forceinline__ void fma_pair(unsigned a, unsigned h, float& lo,
                                                float& hi) {
    float alo = __uint_as_float(a << 16);
    float ahi = __uint_as_float(a & 0xFFFF0000u);
    float hlo = __uint_as_float(h << 16);
    float hhi = __uint_as_float(h & 0xFFFF0000u);
    lo = fmaf(alo, hlo, lo);
    hi = fmaf(ahi, hhi, hi);
}

__global__ __launch_bounds__(256) void aggregate_kernel(
    const int* __restrict__ srcoff, const int* __restrict__ offsets,
    const int* __restrict__ n_id, const u32x4* __restrict__ alf,
    const ushort_t* __restrict__ hfeatq, const float* __restrict__ bias,
    float* __restrict__ out) {
    int wv = threadIdx.x >> 6;
    int d = threadIdx.x & 63;
    const char* hb = (const char*)hfeatq + d * 16;  // lane's 16B column slice
    int n0 = (blockIdx.x * 4 + wv) * 2;             // 2 nodes per wave, exact cover
#pragma unroll 1
    for (int ni = 0; ni < 2; ++ni) {
        int n = n0 + ni;
        int g = n_id[n];
        int beg = offsets[g], end = offsets[g + 1];
        float acc[8] = {};
        int k = beg;
        for (; k + 8 <= end; k += 8) {
            u32x4 sA = __builtin_nontemporal_load((const u32x4*)&srcoff[k]);
            u32x4 sB = __builtin_nontemporal_load((const u32x4*)&srcoff[k + 4]);
            u32x4 gg[8], aa[8];
            gg[0] = *(const u32x4*)(hb + sA.x);
            gg[1] = *(const u32x4*)(hb + sA.y);
            gg[2] = *(const u32x4*)(hb + sA.z);
            gg[3] = *(const u32x4*)(hb + sA.w);
            gg[4] = *(const u32x4*)(hb + sB.x);
            gg[5] = *(const u32x4*)(hb + sB.y);
            gg[6] = *(const u32x4*)(hb + sB.z);
            gg[7] = *(const u32x4*)(hb + sB.w);
#pragma unroll
            for (int i = 0; i < 8; ++i) aa[i] = __builtin_nontemporal_load(&alf[k + i]);
#pragma unroll
            for (int i = 0; i < 8; ++i) {
                fma_pair(aa[i].x, gg[i].x, acc[0], acc[1]);
                fma_pair(aa[i].y, gg[i].y, acc[2], acc[3]);
                fma_pair(aa[i].z, gg[i].z, acc[4], acc[5]);
                fma_pair(aa[i].w, gg[i].w, acc[6], acc[7]);
            }
        }
        for (; k < end; ++k) {
            unsigned so = __builtin_nontemporal_load((const unsigned*)&srcoff[k]);
            u32x4 a0 = __builtin_nontemporal_load(&alf[k]);
            u32x4 g0 = *(const u32x4*)(hb + so);
            fma_pair(a0.x, g0.x, acc[0], acc[1]);
            fma_pair(a0.y, g0.y, acc[2], acc[3]);
            fma_pair(a0.z, g0.z, acc[4], acc[5]);
            fma_pair(a0.w, g0.w, acc[6], acc[7]);
        }
#pragma unroll
        for (int h = 0; h < NHEADS; ++h) {
            int c = h * DHEAD + d;
            __builtin_nontemporal_store(acc[h] + bias[c], &out[(size_t)n * FEAT + c]);
        }
    }
}

extern "C" void kernel_launch(void* const* d_in, const int* in_sizes, int n_in,
                              void* d_out, int out_size, void* d_ws, size_t ws_size,
                              hipStream_t stream) {
    const float* x = (const float*)d_in[0];
    const int* n_id = (const int*)d_in[1];
    const float* attns = (const float*)d_in[2];
    const int* edges = (const int*)d_in[3];
    const float* nw = (const float*)d_in[4];
    const float* W = (const float*)d_in[5];
    const float* bias = (const float*)d_in[6];
    float* out = (float*)d_out;

    char* ws = (char*)d_ws;
    size_t o = 0;
    ushort_t* hfeatq = (ushort_t*)(ws + o); o += 10240000;   // [N][64][8] bf16
    ushort_t* alphab = (ushort_t*)(ws + o); o += 7680000;    // [Etot][8] bf16, dst-sorted
    ushort_t* xb     = (ushort_t*)(ws + o); o += 10240000;
    ushort_t* wbt    = (ushort_t*)(ws + o); o += 524288;
    int* srcoff      = (int*)(ws + o);      o += 1920000;
    int* counts      = (int*)(ws + o);      o += 40000;
    int* cursor      = (int*)(ws + o);      o += 40000;
    int* offsets     = (int*)(ws + o);      o += 40016;
    int* inv         = (int*)(ws + o);      o += 40000;
    // total ~30.8 MB

    hipMemsetAsync(counts, 0, 80000, stream);  // counts + cursor (adjacent)
    prep_fused_kernel<<<CVTX_BLKS + CVTW_BLKS + HIST_BLKS + INV_BLKS, 256, 0, stream>>>(
        x, xb, W, wbt, edges, counts, n_id, inv);
    scan_kernel<<<1, 1024, 0, stream>>>(counts, offsets);
    scatter_kernel<<<HIST_BLKS, 256, 0, stream>>>(edges, inv, offsets, cursor, attns, nw,
                                                  srcoff, alphab);
    dim3 ggrid(FEAT / 128, (NNODES + 127) / 128);
    gemm_mfma_kernel<<<ggrid, 256, 0, stream>>>(xb, wbt, hfeatq);
    aggregate_kernel<<<(NNODES + 7) / 8, 256, 0, stream>>>(srcoff, offsets, n_id,
                                                           (const u32x4*)alphab, hfeatq,
                                                           bias, out);
}

// Round 7
// 157.789 us; speedup vs baseline: 1.2610x; 1.2269x over previous
//
#include <hip/hip_runtime.h>

#define NNODES 10000
#define NHEADS 8
#define DHEAD 64
#define FEAT 512
#define NNETS 3
#define EDGES 160000
#define ETOT (NNETS * EDGES)
#define NBUCK 4
#define BUCKSZ 2500             // nodes per src-bucket
#define NKEY (NNODES * NBUCK)   // 40000 counting-sort keys

#define CVTX_BLKS 5000          // NNODES*FEAT/4/256
#define CVTW_BLKS 256           // (FEAT/32)^2
#define HIST_BLKS 1875          // ETOT/256
#define INV_BLKS 40             // ceil(NNODES/256)

typedef unsigned short ushort_t;
typedef __bf16 bf16x8 __attribute__((ext_vector_type(8)));
typedef float f32x4 __attribute__((ext_vector_type(4)));
typedef unsigned u32x4 __attribute__((ext_vector_type(4)));

static __device__ __forceinline__ ushort_t f2b(float f) {
    unsigned u = __float_as_uint(f);
    unsigned r = u + 0x7FFF + ((u >> 16) & 1);   // RNE
    return (ushort_t)(r >> 16);
}

static __device__ __forceinline__ void mfma16(f32x4& d, bf16x8 a, bf16x8 b) {
    asm volatile("v_mfma_f32_16x16x32_bf16 %0, %1, %2, %0" : "+v"(d) : "v"(a), "v"(b));
}

#define GLDS(gp, lp)                                                                     \
    __builtin_amdgcn_global_load_lds((const __attribute__((address_space(1))) void*)(gp), \
                                     (__attribute__((address_space(3))) void*)(lp), 16, 0, 0)

// ---- fused prep: cvt_x | cvt_wt | hist(dst*4 + srcbucket) | build_inv ----
__global__ __launch_bounds__(256) void prep_fused_kernel(
    const float* __restrict__ x, ushort_t* __restrict__ xb, const float* __restrict__ W,
    ushort_t* __restrict__ wbt, const int* __restrict__ edges, int* __restrict__ counts,
    const int* __restrict__ n_id, int* __restrict__ inv) {
    __shared__ float tile[32][33];
    int b = blockIdx.x;
    int t = threadIdx.x;
    if (b < CVTX_BLKS) {
        int i = (b * 256 + t) * 4;
        float4 v = *(const float4*)(x + i);
        ushort4 o;
        o.x = f2b(v.x);
        o.y = f2b(v.y);
        o.z = f2b(v.z);
        o.w = f2b(v.w);
        *(ushort4*)(xb + i) = o;
    } else if (b < CVTX_BLKS + CVTW_BLKS) {
        int bb = b - CVTX_BLKS;
        int n0 = (bb & 15) * 32, k0 = (bb >> 4) * 32;
        int r = t >> 3, c4 = (t & 7) * 4;
        float4 v = *(const float4*)(&W[(size_t)(k0 + r) * FEAT + n0 + c4]);
        tile[r][c4 + 0] = v.x;
        tile[r][c4 + 1] = v.y;
        tile[r][c4 + 2] = v.z;
        tile[r][c4 + 3] = v.w;
        __syncthreads();
        ushort4 o;
        o.x = f2b(tile[c4 + 0][r]);
        o.y = f2b(tile[c4 + 1][r]);
        o.z = f2b(tile[c4 + 2][r]);
        o.w = f2b(tile[c4 + 3][r]);
        *(ushort4*)(&wbt[(size_t)(n0 + r) * FEAT + k0 + c4]) = o;
    } else if (b < CVTX_BLKS + CVTW_BLKS + HIST_BLKS) {
        int eid = (b - CVTX_BLKS - CVTW_BLKS) * 256 + t;
        int net = eid / EDGES;
        int e = eid - net * EDGES;
        int srcg = edges[net * (2 * EDGES) + e];
        int dstg = edges[net * (2 * EDGES) + EDGES + e];
        atomicAdd(&counts[dstg * NBUCK + srcg / BUCKSZ], 1);
    } else {
        int i = (b - CVTX_BLKS - CVTW_BLKS - HIST_BLKS) * 256 + t;
        if (i < NNODES) inv[n_id[i]] = i;
    }
}

// ---- shfl-based exclusive scan of counts[NKEY] -> offsets[NKEY+1] ----
// 1024 threads; threads 0..999 each own 40 contiguous counters.
__global__ __launch_bounds__(1024) void scan_kernel(const int* __restrict__ counts,
                                                    int* __restrict__ offsets) {
    __shared__ int wincl[16];
    int t = threadIdx.x;
    int ln = t & 63;
    int w = t >> 6;
    int4 v[10];
    int mysum = 0;
    if (t < 1000) {
        const int4* cp = (const int4*)(counts + t * 40);
#pragma unroll
        for (int i = 0; i < 10; ++i) {
            v[i] = cp[i];
            mysum += v[i].x + v[i].y + v[i].z + v[i].w;
        }
    }
    // inclusive scan of thread sums within wave
    int s = mysum;
#pragma unroll
    for (int o = 1; o < 64; o <<= 1) {
        int u = __shfl_up(s, o, 64);
        if (ln >= o) s += u;
    }
    if (ln == 63) wincl[w] = s;
    __syncthreads();
    if (w == 0) {
        int ws = (ln < 16) ? wincl[ln] : 0;
#pragma unroll
        for (int o = 1; o < 16; o <<= 1) {
            int u = __shfl_up(ws, o, 64);
            if (ln >= o) ws += u;
        }
        if (ln < 16) wincl[ln] = ws;
    }
    __syncthreads();
    int base = ((w > 0) ? wincl[w - 1] : 0) + s - mysum;  // global exclusive base
    if (t < 1000) {
        int running = base;
        int* op = offsets + t * 40;
#pragma unroll
        for (int i = 0; i < 10; ++i) {
            op[i * 4 + 0] = running; running += v[i].x;
            op[i * 4 + 1] = running; running += v[i].y;
            op[i * 4 + 2] = running; running += v[i].z;
            op[i * 4 + 3] = running; running += v[i].w;
        }
        if (t == 999) offsets[NKEY] = running;
    }
}

// ---- scatter by (dst, srcbucket): byte-offset src + [Etot][8] bf16 alpha ----
__global__ __launch_bounds__(256) void scatter_kernel(const int* __restrict__ edges,
                                                      const int* __restrict__ inv,
                                                      const int* __restrict__ offsets,
                                                      int* __restrict__ cursor,
                                                      const float* __restrict__ attns,
                                                      const float* __restrict__ nw,
                                                      int* __restrict__ srcoff,
                                                      ushort_t* __restrict__ alphab) {
    int eid = blockIdx.x * 256 + threadIdx.x;
    int net = eid / EDGES;
    int e = eid - net * EDGES;
    int srcg = edges[net * (2 * EDGES) + e];
    int dstg = edges[net * (2 * EDGES) + EDGES + e];
    int key = dstg * NBUCK + srcg / BUCKSZ;
    int pos = offsets[key] + atomicAdd(&cursor[key], 1);
    srcoff[pos] = inv[srcg] << 10;  // byte offset of hfeat row (1024 B/row)
    float4 A0 = *(const float4*)(&attns[(size_t)eid * NHEADS]);
    float4 A1 = *(const float4*)(&attns[(size_t)eid * NHEADS + 4]);
    ushort4 o0, o1;
    o0.x = f2b(A0.x * nw[0 * NNETS + net]);
    o0.y = f2b(A0.y * nw[1 * NNETS + net]);
    o0.z = f2b(A0.z * nw[2 * NNETS + net]);
    o0.w = f2b(A0.w * nw[3 * NNETS + net]);
    o1.x = f2b(A1.x * nw[4 * NNETS + net]);
    o1.y = f2b(A1.y * nw[5 * NNETS + net]);
    o1.z = f2b(A1.z * nw[6 * NNETS + net]);
    o1.w = f2b(A1.w * nw[7 * NNETS + net]);
    *(ushort4*)(&alphab[(size_t)pos * NHEADS]) = o0;
    *(ushort4*)(&alphab[(size_t)pos * NHEADS + 4]) = o1;
}

// ---- hfeat = xb @ wbt^T (bf16 MFMA, 128x128 tile), epilogue writes [N][D][H] ----
__global__ __launch_bounds__(256) void gemm_mfma_kernel(const ushort_t* __restrict__ xb,
                                                        const ushort_t* __restrict__ wbt,
                                                        ushort_t* __restrict__ Cq) {
    __shared__ ushort_t Alds[128 * 32];
    __shared__ ushort_t Blds[128 * 32];
    const int t = threadIdx.x;
    const int wv = t >> 6;
    const int l = t & 63;
    const int lane15 = l & 15;
    const int hi = l >> 4;
    const int r0 = blockIdx.y * 128;
    const int c0 = blockIdx.x * 128;
    const int WR = (wv >> 1) * 64;
    const int WC = (wv & 1) * 64;

    const int srow = (wv << 4) + (l >> 2);
    const int scol = (l & 3) << 3;
    const ushort_t* Ab0 = xb + (size_t)min(r0 + srow, NNODES - 1) * FEAT + scol;
    const ushort_t* Ab1 = xb + (size_t)min(r0 + 64 + srow, NNODES - 1) * FEAT + scol;
    const ushort_t* Bb0 = wbt + (size_t)(c0 + srow) * FEAT + scol;
    const ushort_t* Bb1 = wbt + (size_t)(c0 + 64 + srow) * FEAT + scol;
    ushort_t* Al0 = &Alds[wv * 512];
    ushort_t* Al1 = &Alds[2048 + wv * 512];
    ushort_t* Bl0 = &Blds[wv * 512];
    ushort_t* Bl1 = &Blds[2048 + wv * 512];

    f32x4 acc[4][4] = {};

    for (int k0 = 0; k0 < FEAT; k0 += 32) {
        GLDS(Ab0 + k0, Al0);
        GLDS(Ab1 + k0, Al1);
        GLDS(Bb0 + k0, Bl0);
        GLDS(Bb1 + k0, Bl1);
        __syncthreads();
        bf16x8 a[4], b[4];
        const ushort_t* Ap = &Alds[(WR + lane15) * 32 + hi * 8];
        const ushort_t* Bp = &Blds[(WC + lane15) * 32 + hi * 8];
#pragma unroll
        for (int m = 0; m < 4; ++m) a[m] = *(const bf16x8*)(Ap + m * 512);
#pragma unroll
        for (int n = 0; n < 4; ++n) b[n] = *(const bf16x8*)(Bp + n * 512);
#pragma unroll
        for (int m = 0; m < 4; ++m)
#pragma unroll
            for (int n = 0; n < 4; ++n) mfma16(acc[m][n], a[m], b[n]);
        __syncthreads();
    }
    asm volatile("s_nop 7\n\ts_nop 7\n\ts_nop 7" ::);  // MFMA->VALU hazard guard
    const int h = (c0 + WC) >> 6;  // head fixed per wave (64-col span)
#pragma unroll
    for (int m = 0; m < 4; ++m) {
#pragma unroll
        for (int rr = 0; rr < 4; ++rr) {
            int row = r0 + WR + m * 16 + hi * 4 + rr;
            if (row < NNODES) {
#pragma unroll
                for (int n = 0; n < 4; ++n) {
                    int d = n * 16 + lane15;  // 0..63 within head
                    Cq[(size_t)row * FEAT + d * NHEADS + h] = f2b(acc[m][n][rr]);
                }
            }
        }
    }
}

// ---- aggregation: 128-thread blocks, 1 node per wave, lane = column d, unroll 8 ----
static __device__ __forceinline__ void fma_pair(unsigned a, unsigned h, float& lo,
                                                float& hi) {
    float alo = __uint_as_float(a << 16);
    float ahi = __uint_as_float(a & 0xFFFF0000u);
    float hlo = __uint_as_float(h << 16);
    float hhi = __uint_as_float(h & 0xFFFF0000u);
    lo = fmaf(alo, hlo, lo);
    hi = fmaf(ahi, hhi, hi);
}

__global__ __launch_bounds__(128) void aggregate_kernel(
    const int* __restrict__ srcoff, const int* __restrict__ offsets,
    const int* __restrict__ n_id, const u32x4* __restrict__ alf,
    const ushort_t* __restrict__ hfeatq, const float* __restrict__ bias,
    float* __restrict__ out) {
    int wv = threadIdx.x >> 6;
    int d = threadIdx.x & 63;
    const char* hb = (const char*)hfeatq + d * 16;  // lane's 16B column slice
    int n = blockIdx.x * 2 + wv;
    int g = n_id[n];
    int beg = offsets[g * NBUCK], end = offsets[g * NBUCK + NBUCK];
    float acc[8] = {};
    int k = beg;
    for (; k + 8 <= end; k += 8) {
        u32x4 sA = __builtin_nontemporal_load((const u32x4*)&srcoff[k]);
        u32x4 sB = __builtin_nontemporal_load((const u32x4*)&srcoff[k + 4]);
        u32x4 gg[8], aa[8];
        gg[0] = *(const u32x4*)(hb + sA.x);
        gg[1] = *(const u32x4*)(hb + sA.y);
        gg[2] = *(const u32x4*)(hb + sA.z);
        gg[3] = *(const u32x4*)(hb + sA.w);
        gg[4] = *(const u32x4*)(hb + sB.x);
        gg[5] = *(const u32x4*)(hb + sB.y);
        gg[6] = *(const u32x4*)(hb + sB.z);
        gg[7] = *(const u32x4*)(hb + sB.w);
#pragma unroll
        for (int i = 0; i < 8; ++i) aa[i] = __builtin_nontemporal_load(&alf[k + i]);
#pragma unroll
        for (int i = 0; i < 8; ++i) {
            fma_pair(aa[i].x, gg[i].x, acc[0], acc[1]);
            fma_pair(aa[i].y, gg[i].y, acc[2], acc[3]);
            fma_pair(aa[i].z, gg[i].z, acc[4], acc[5]);
            fma_pair(aa[i].w, gg[i].w, acc[6], acc[7]);
        }
    }
    for (; k < end; ++k) {
        unsigned so = __builtin_nontemporal_load((const unsigned*)&srcoff[k]);
        u32x4 a0 = __builtin_nontemporal_load(&alf[k]);
        u32x4 g0 = *(const u32x4*)(hb + so);
        fma_pair(a0.x, g0.x, acc[0], acc[1]);
        fma_pair(a0.y, g0.y, acc[2], acc[3]);
        fma_pair(a0.z, g0.z, acc[4], acc[5]);
        fma_pair(a0.w, g0.w, acc[6], acc[7]);
    }
#pragma unroll
    for (int h = 0; h < NHEADS; ++h) {
        int c = h * DHEAD + d;
        __builtin_nontemporal_store(acc[h] + bias[c], &out[(size_t)n * FEAT + c]);
    }
}

extern "C" void kernel_launch(void* const* d_in, const int* in_sizes, int n_in,
                              void* d_out, int out_size, void* d_ws, size_t ws_size,
                              hipStream_t stream) {
    const float* x = (const float*)d_in[0];
    const int* n_id = (const int*)d_in[1];
    const float* attns = (const float*)d_in[2];
    const int* edges = (const int*)d_in[3];
    const float* nw = (const float*)d_in[4];
    const float* W = (const float*)d_in[5];
    const float* bias = (const float*)d_in[6];
    float* out = (float*)d_out;

    char* ws = (char*)d_ws;
    size_t o = 0;
    ushort_t* hfeatq = (ushort_t*)(ws + o); o += 10240000;   // [N][64][8] bf16
    ushort_t* alphab = (ushort_t*)(ws + o); o += 7680000;    // [Etot][8] bf16, sorted
    ushort_t* xb     = (ushort_t*)(ws + o); o += 10240000;
    ushort_t* wbt    = (ushort_t*)(ws + o); o += 524288;
    int* srcoff      = (int*)(ws + o);      o += 1920000;
    int* counts      = (int*)(ws + o);      o += 160000;     // NKEY
    int* cursor      = (int*)(ws + o);      o += 160000;     // NKEY
    int* offsets     = (int*)(ws + o);      o += 160004;     // NKEY+1
    int* inv         = (int*)(ws + o);      o += 40000;
    // total ~31.3 MB

    hipMemsetAsync(counts, 0, 320000, stream);  // counts + cursor (adjacent)
    prep_fused_kernel<<<CVTX_BLKS + CVTW_BLKS + HIST_BLKS + INV_BLKS, 256, 0, stream>>>(
        x, xb, W, wbt, edges, counts, n_id, inv);
    scan_kernel<<<1, 1024, 0, stream>>>(counts, offsets);
    scatter_kernel<<<HIST_BLKS, 256, 0, stream>>>(edges, inv, offsets, cursor, attns, nw,
                                                  srcoff, alphab);
    dim3 ggrid(FEAT / 128, (NNODES + 127) / 128);
    gemm_mfma_kernel<<<ggrid, 256, 0, stream>>>(xb, wbt, hfeatq);
    aggregate_kernel<<<NNODES / 2, 128, 0, stream>>>(srcoff, offsets, n_id,
                                                     (const u32x4*)alphab, hfeatq,
                                                     bias, out);
}